// Round 2
// baseline (699.922 us; speedup 1.0000x reference)
//
#include <hip/hip_runtime.h>

// Power retention (deg-2), B=2 T=4096 H=16 D=64, CHUNK=64, E=2080.
// Round 5: segmented scan (SEG=2) + correction kernel.
//  - scan: each (bh,eh,dh) chain split into two 32-chunk segments; seg1
//    starts from zero state (gate folds are chunk-local). 1024 blocks ->
//    4 blocks/CU resident (was 2), hiding the per-chunk latency chain.
//    Seg0 writes its final hatted state (f32) + sk to Sloc/skloc.
//  - corr_kernel: for seg1 tokens, adds D_m * (pq . S_init) into part and
//    D_m * (pq . sk_init) into den, where S_init = dec0*S0hat + Sloc and
//    D_m = running product of chunk decays within seg1. MM1-only, fixed
//    state, no serial chain -> fully parallel.
// prep + intra_merge unchanged from round 4.

#define B_ 2
#define T_ 4096
#define H_ 16
#define D_ 64
#define CHUNK_ 64
#define NCH_ 64
#define SEGCH_ 32        // chunks per segment
#define E_ 2080
#define EH_ 8
#define NBLK_ 36         // (i, jb) 8-wide blocks per eh-slice (288/8, exact)
#define EPAD_ 288        // NBLK_*8
#define NKS_ 9           // MM1 K-steps of 32
#define STR_ 296         // sT row stride (f16), 592B = 148 dw == 20 mod 32
#define OUTN_ 8388608    // B*T*H*D

typedef __attribute__((ext_vector_type(8))) _Float16 half8v;
typedef __attribute__((ext_vector_type(4))) float floatx4;

union U8 { half8v h; unsigned u[4]; ushort s[8]; };

static __device__ __forceinline__ float wave_iscan(float g, int lane) {
    #pragma unroll
    for (int off = 1; off < 64; off <<= 1) {
        float o = __shfl_up(g, off, 64);
        if (lane >= off) g += o;
    }
    return g;
}

typedef const __attribute__((address_space(1))) unsigned int* gas1_t;
typedef __attribute__((address_space(3))) unsigned int* las3_t;
static __device__ __forceinline__ void gload16(const void* g, void* l) {
    __builtin_amdgcn_global_load_lds((gas1_t)g, (las3_t)l, 16, 0, 0);
}

// ---------------- Prep: gates + scales + cvt + swizzled transpose ----------------
__global__ __launch_bounds__(256) void prep_kernel(
    const float* __restrict__ q, const float* __restrict__ k, const float* __restrict__ v,
    const float* __restrict__ gate,
    _Float16* __restrict__ qh, _Float16* __restrict__ khT, _Float16* __restrict__ vhT,
    float* __restrict__ gse_buf)
{
    const int bid = blockIdx.x;          // bh*64 + n
    const int bh = bid >> 6, n = bid & 63;
    const int b = bh >> 4, h = bh & 15;
    const int t0 = n * CHUNK_;
    const int tid = threadIdx.x;

    __shared__ float cgs[64];
    __shared__ float tbuf[64 * 68];

    if (tid < 64) {
        float g = gate[((size_t)(b * T_ + t0) + tid) * H_ + h];
        cgs[tid] = wave_iscan(g, tid);
    }
    __syncthreads();
    const float gs = cgs[63];
    if (tid == 0) gse_buf[bid] = __expf(gs);

    const int c = tid >> 2, dq = (tid & 3) * 16;
    const size_t gbase = ((size_t)(b * T_ + t0 + c) * H_ + h) * 64 + dq;
    const size_t obase = (size_t)bid * 4096;

    // ---- q~ (no transpose, swizzled d-groups)
    {
        float qsc = 0.125f * __expf(0.5f * cgs[c]);
        #pragma unroll
        for (int g8 = 0; g8 < 2; ++g8) {
            float4 a0 = *(const float4*)(q + gbase + g8 * 8);
            float4 a1 = *(const float4*)(q + gbase + g8 * 8 + 4);
            half8v hv;
            hv[0] = (_Float16)(a0.x * qsc); hv[1] = (_Float16)(a0.y * qsc);
            hv[2] = (_Float16)(a0.z * qsc); hv[3] = (_Float16)(a0.w * qsc);
            hv[4] = (_Float16)(a1.x * qsc); hv[5] = (_Float16)(a1.y * qsc);
            hv[6] = (_Float16)(a1.z * qsc); hv[7] = (_Float16)(a1.w * qsc);
            int grp = (dq >> 3) + g8;
            *(half8v*)&qh[obase + (size_t)(c * 64) + ((grp ^ (c & 7)) << 3)] = hv;
        }
    }
    // ---- k~ -> LDS [c][d]
    {
        float ksc = __expf(0.5f * (gs - cgs[c]));
        #pragma unroll
        for (int i = 0; i < 4; ++i) {
            float4 a = *(const float4*)(k + gbase + i * 4);
            float4 sa; sa.x = a.x * ksc; sa.y = a.y * ksc; sa.z = a.z * ksc; sa.w = a.w * ksc;
            *(float4*)&tbuf[c * 68 + dq + i * 4] = sa;
        }
    }
    __syncthreads();
    {   // transposed, swizzled store of k~^T
        int d = tid & 63, f = (d & 7) ^ (d >> 3);
        #pragma unroll
        for (int gg = 0; gg < 2; ++gg) {
            int cg = (tid >> 6) * 2 + gg;
            half8v hv;
            #pragma unroll
            for (int j = 0; j < 8; ++j) hv[j] = (_Float16)tbuf[(cg * 8 + j) * 68 + d];
            *(half8v*)&khT[obase + (size_t)(d * 64) + ((cg ^ f) << 3)] = hv;
        }
    }
    __syncthreads();
    {   // v -> LDS (no scale)
        #pragma unroll
        for (int i = 0; i < 4; ++i)
            *(float4*)&tbuf[c * 68 + dq + i * 4] = *(const float4*)(v + gbase + i * 4);
    }
    __syncthreads();
    {   // transposed, swizzled store of v^T (f over dl = d&31)
        int d = tid & 63, dl = d & 31, f = (dl & 7) ^ (dl >> 3);
        #pragma unroll
        for (int gg = 0; gg < 2; ++gg) {
            int cg = (tid >> 6) * 2 + gg;
            half8v hv;
            #pragma unroll
            for (int j = 0; j < 8; ++j) hv[j] = (_Float16)tbuf[(cg * 8 + j) * 68 + d];
            *(half8v*)&vhT[obase + (size_t)(d * 64) + ((cg ^ f) << 3)] = hv;
        }
    }
}

// ---------------- Kernel B: segmented scan (f16 MFMA), SEG=2 ----------------
__global__ __launch_bounds__(512, 4) void scan_kernel(
    const _Float16* __restrict__ qh, const _Float16* __restrict__ khT,
    const _Float16* __restrict__ vhT, const float* __restrict__ gse_buf,
    const float* __restrict__ S0, const float* __restrict__ sk0,
    float* __restrict__ den_buf, _Float16* __restrict__ part,
    float* __restrict__ Sloc, float* __restrict__ skloc)
{
    const int bid = blockIdx.x;
    // XCD swizzle: 16 inner blocks of one (bh,seg) share bid&7 -> same XCD
    const int bhseg = (bid & 7) * 8 + (bid >> 7);
    const int inner = (bid >> 3) & 15;
    const int eh = inner & 7, dh = inner >> 3;
    const int seg = bhseg & 1, bh = bhseg >> 1;
    const int gn0 = seg * SEGCH_;
    const int tid = threadIdx.x, lane = tid & 63, w = tid >> 6;   // w 0..7
    const int nlane = lane & 15, quad = lane >> 4;

    __shared__ __align__(16) _Float16 sT[32 * STR_];     // S^T[d_local][e], 2-bit XOR swz
    __shared__ __align__(16) _Float16 kTs[64 * 64];      // k~^T (linear, global-preswizzled)
    __shared__ __align__(16) _Float16 qsh[64 * 64];      // q~   (linear, global-preswizzled)
    __shared__ __align__(16) _Float16 vTs[32 * 64];      // v^T half (linear, preswizzled)
    __shared__ __align__(16) _Float16 sk_s[EPAD_];
    __shared__ int blk_s[NBLK_];                         // i | (jb<<8)

    // ---- build (i, jb) block table for this slice
    for (int t = tid; t < NBLK_; t += 512) {
        int g = eh * NBLK_ + t;
        int i = 0;
        while (g >= 8 - (i >> 3)) { g -= 8 - (i >> 3); ++i; }
        int jb = (i >> 3) + g;
        blk_s[t] = i | (jb << 8);
    }
    __syncthreads();

    const _Float16* qsrc = qh + ((size_t)(bh * NCH_) + gn0) * 4096;
    const _Float16* ksrc = khT + ((size_t)(bh * NCH_) + gn0) * 4096;
    const _Float16* vsrc = vhT + ((size_t)(bh * NCH_) + gn0) * 4096 + dh * 2048;

    // issue q~(0) staging now; drains at the pre-loop barrier
    gload16(qsrc + tid * 8, &qsh[tid * 8]);

    // ---- sk init (seg0: hatted sk0; seg1: zeros)
    for (int e = tid; e < EPAD_; e += 512) {
        int bv = blk_s[e >> 3];
        int i = bv & 255, j8 = (bv >> 8) * 8 + (e & 7);
        float sv = 0.f;
        if (seg == 0 && j8 >= i) {
            int er = (i * (129 - i)) / 2 + (j8 - i);
            float coef = (j8 == i) ? 1.f : 1.41421356237f;
            sv = sk0[(size_t)bh * E_ + er] * coef;
        }
        sk_s[e] = (_Float16)sv;
    }
    // ---- sT init (seg0: hatted S0; seg1: zeros), 2-bit XOR swizzled columns
    for (int p = tid; p < 32 * EPAD_; p += 512) {
        int dl = p / EPAD_;
        int e = p - dl * EPAD_;
        int bv = blk_s[e >> 3];
        int i = bv & 255, j8 = (bv >> 8) * 8 + (e & 7);
        float sv = 0.f;
        if (seg == 0 && j8 >= i) {
            int er = (i * (129 - i)) / 2 + (j8 - i);
            float coef = (j8 == i) ? 1.f : 1.41421356237f;
            sv = S0[((size_t)bh * E_ + er) * 64 + dh * 32 + dl] * coef;
        }
        int col8 = e >> 3, gsw = (dl >> 2) & 3;
        int pc = ((col8 & ~3) | ((col8 & 3) ^ gsw)) * 8 + (e & 7);
        sT[dl * STR_ + pc] = (_Float16)sv;
    }

    // ---- wave roles
    const int mt = w & 3, nt0 = w >> 2;
    const int c_row = mt * 16 + nlane;
    const bool den_w = (w < 4) && (dh == 0);
    const int NTS = (w < 2) ? 3 : 2;          // waves 0,1 own a 3rd tile (16,17)

    // ---- resident S fragments: wave owns tiles {w, w+8, (w+16 if w<2)} x mtv{0,1}(+sk)
    floatx4 res[3][2];
    floatx4 resk[3];
    #pragma unroll
    for (int ts = 0; ts < 3; ++ts) {
        res[ts][0] = (floatx4){0.f, 0.f, 0.f, 0.f};
        res[ts][1] = (floatx4){0.f, 0.f, 0.f, 0.f};
        resk[ts]   = (floatx4){0.f, 0.f, 0.f, 0.f};
        if (ts >= NTS || seg != 0) continue;
        int tile = w + 8 * ts;
        int e = tile * 16 + nlane;
        int bv = blk_s[e >> 3];
        int i = bv & 255, j8 = (bv >> 8) * 8 + (e & 7);
        if (j8 >= i) {
            int er = (i * (129 - i)) / 2 + (j8 - i);
            float coef = (j8 == i) ? 1.f : 1.41421356237f;
            #pragma unroll
            for (int m = 0; m < 2; ++m) {
                floatx4 t4 = *(const floatx4*)&S0[((size_t)bh * E_ + er) * 64 + dh * 32 + m * 16 + quad * 4];
                #pragma unroll
                for (int r = 0; r < 4; ++r) res[ts][m][r] = t4[r] * coef;
            }
            if (dh == 0 && quad == 0) resk[ts][0] = sk0[(size_t)bh * E_ + er] * coef;
        }
    }

    // ---- chunk-invariant MM1 addresses (byte offsets)
    int qiu_off[NKS_], qrow_off[NKS_];
    #pragma unroll
    for (int ks = 0; ks < NKS_; ++ks) {
        int bv = blk_s[ks * 4 + quad];
        int ib = bv & 255, jb = bv >> 8;
        qiu_off[ks]  = (c_row * 64 + (((ib >> 3) ^ (c_row & 7)) << 3) + (ib & 7)) * 2;
        qrow_off[ks] = (c_row * 64 + ((jb ^ (c_row & 7)) << 3)) * 2;
    }
    const int b0_off = ((nt0 * 16 + nlane) * STR_ + ((quad ^ ((nlane >> 2) & 3)) << 3)) * 2;

    // ---- chunk-invariant MM2 addresses + m2 splats
    int pa_off[3], pb_off[3], stw_off[3], eidx[3];
    unsigned m2sp[3];
    #pragma unroll
    for (int ts = 0; ts < 3; ++ts) {
        pa_off[ts] = pb_off[ts] = stw_off[ts] = eidx[ts] = 0; m2sp[ts] = 0;
        if (ts >= NTS) continue;
        int tile = w + 8 * ts, e = tile * 16 + nlane;
        int bv = blk_s[e >> 3];
        int ib = bv & 255, j8 = (bv >> 8) * 8 + (e & 7);
        int fib = (ib & 7) ^ (ib >> 3), fj8 = (j8 & 7) ^ (j8 >> 3);
        pa_off[ts] = (ib * 64 + ((quad ^ fib) << 3)) * 2;
        pb_off[ts] = (j8 * 64 + ((quad ^ fj8) << 3)) * 2;
        int col8 = e >> 3;
        int pc = ((col8 & ~3) | ((col8 & 3) ^ quad)) * 8 + (e & 7);
        stw_off[ts] = (quad * 4 * STR_ + pc) * 2;
        eidx[ts] = e;
        unsigned hv = (j8 < ib) ? 0u : ((j8 == ib) ? 0x3C00u : 0x4000u);  // {0,1,2} coef^2
        m2sp[ts] = (hv << 16) | hv;
    }
    int af_off[2];
    #pragma unroll
    for (int m = 0; m < 2; ++m) {
        int row = m * 16 + nlane;
        int fr = (row & 7) ^ (row >> 3);
        af_off[m] = (row * 64 + ((quad ^ fr) << 3)) * 2;
    }
    half8v af_sk = (half8v){0, 0, 0, 0, 0, 0, 0, 0};
    if (nlane == 0) af_sk = (half8v){1, 1, 1, 1, 1, 1, 1, 1};

    _Float16* ppart = part + (size_t)eh * OUTN_ + (((size_t)bh * T_) << 6) + dh * 32 + nt0 * 16 + nlane;

    __syncthreads();   // B0: init + blk reads done; q~(0) drained

    for (int n = 0; n < SEGCH_; ++n) {
        const int gn = gn0 + n;
        // issue k~/v staging for THIS chunk; drains at B2 (hidden under MM1)
        gload16(ksrc + (size_t)n * 4096 + tid * 8, &kTs[tid * 8]);
        if (tid < 256) gload16(vsrc + (size_t)n * 4096 + tid * 8, &vTs[tid * 8]);
        const float gsev = gse_buf[bh * NCH_ + gn];

        // ======== MM1: num[c][d] = pq . S-hat ; den rides as MFMA with sk column
        {
            floatx4 acc0 = {0.f, 0.f, 0.f, 0.f};
            floatx4 acc1 = {0.f, 0.f, 0.f, 0.f};
            #pragma unroll
            for (int ks = 0; ks < NKS_; ++ks) {
                ushort qiu = *(const ushort*)((const char*)qsh + qiu_off[ks]);
                unsigned qi2 = ((unsigned)qiu << 16) | qiu;
                U8 qv; qv.u[0] = qi2; qv.u[1] = qi2; qv.u[2] = qi2; qv.u[3] = qi2;
                half8v qrow = *(const half8v*)((const char*)qsh + qrow_off[ks]);
                half8v afr = qv.h * qrow;            // no m8: invalid sT cols are 0
                half8v b0 = *(const half8v*)((const char*)sT + b0_off + ks * 64);
                acc0 = __builtin_amdgcn_mfma_f32_16x16x32_f16(afr, b0, acc0, 0, 0, 0);
                if (den_w) {
                    half8v b1 = (half8v){0, 0, 0, 0, 0, 0, 0, 0};
                    if (nlane == 0) b1 = *(const half8v*)&sk_s[ks * 32 + quad * 8];
                    acc1 = __builtin_amdgcn_mfma_f32_16x16x32_f16(afr, b1, acc1, 0, 0, 0);
                }
            }
            _Float16* pp = ppart + ((size_t)(gn * CHUNK_ + mt * 16 + quad * 4) << 6);
            #pragma unroll
            for (int r = 0; r < 4; ++r) pp[(size_t)r << 6] = (_Float16)acc0[r];
            if (den_w && nlane == 0) {
                #pragma unroll
                for (int r = 0; r < 4; ++r)
                    atomicAdd(&den_buf[(size_t)bh * T_ + gn * CHUNK_ + mt * 16 + quad * 4 + r], acc1[r]);
            }
        }
        __syncthreads();   // B2: MM1 LDS reads done; k~/v staged

        // issue q~(n+1); drains at B1 (hidden under MM2)
        if (n + 1 < SEGCH_) gload16(qsrc + (size_t)(n + 1) * 4096 + tid * 8, &qsh[tid * 8]);

        // ======== MM2: S-hat = gse*S-hat + v^T . pk ; sk rides as ones-row unit
        #pragma unroll
        for (int ts = 0; ts < 3; ++ts) {
            if (ts >= NTS) continue;
            #pragma unroll
            for (int m = 0; m < 2; ++m)
                #pragma unroll
                for (int r = 0; r < 4; ++r) res[ts][m][r] *= gsev;
            if (dh == 0) resk[ts][0] *= gsev;
        }
        #pragma unroll
        for (int k2 = 0; k2 < 2; ++k2) {
            const int xo = k2 * 64;    // group bit2 flip == byte bit6 flip
            half8v af0 = *(const half8v*)((const char*)vTs + (af_off[0] ^ xo));
            half8v af1 = *(const half8v*)((const char*)vTs + (af_off[1] ^ xo));
            #pragma unroll
            for (int ts = 0; ts < 3; ++ts) {
                if (ts >= NTS) continue;
                half8v pa = *(const half8v*)((const char*)kTs + (pa_off[ts] ^ xo));
                half8v pb = *(const half8v*)((const char*)kTs + (pb_off[ts] ^ xo));
                U8 mv; mv.u[0] = m2sp[ts]; mv.u[1] = m2sp[ts]; mv.u[2] = m2sp[ts]; mv.u[3] = m2sp[ts];
                half8v bfr = pa * pb * mv.h;
                res[ts][0] = __builtin_amdgcn_mfma_f32_16x16x32_f16(af0, bfr, res[ts][0], 0, 0, 0);
                res[ts][1] = __builtin_amdgcn_mfma_f32_16x16x32_f16(af1, bfr, res[ts][1], 0, 0, 0);
                if (dh == 0)
                    resk[ts] = __builtin_amdgcn_mfma_f32_16x16x32_f16(af_sk, bfr, resk[ts], 0, 0, 0);
            }
        }
        // write back sT (swizzled, 2-way max) and sk
        #pragma unroll
        for (int ts = 0; ts < 3; ++ts) {
            if (ts >= NTS) continue;
            #pragma unroll
            for (int m = 0; m < 2; ++m)
                #pragma unroll
                for (int r = 0; r < 4; ++r)
                    *(_Float16*)((char*)sT + stw_off[ts] + (m * 16 * STR_ + r * STR_) * 2) =
                        (_Float16)res[ts][m][r];
            if (dh == 0 && quad == 0) sk_s[eidx[ts]] = (_Float16)resk[ts][0];
        }
        __syncthreads();   // B1: sT/sk visible; q~(n+1) drained
    }

    // ---- seg0: export final hatted local state (f32) for the correction pass
    if (seg == 0) {
        float* SL = Sloc + (size_t)(((bh << 3) + eh) * 2 + dh) * 9216;
        #pragma unroll
        for (int ts = 0; ts < 3; ++ts) {
            if (ts >= NTS) continue;
            int e = (w + 8 * ts) * 16 + nlane;
            #pragma unroll
            for (int m = 0; m < 2; ++m)
                #pragma unroll
                for (int r = 0; r < 4; ++r)
                    SL[e * 32 + m * 16 + quad * 4 + r] = res[ts][m][r];
            if (dh == 0 && quad == 0)
                skloc[(size_t)((bh << 3) + eh) * EPAD_ + e] = resk[ts][0];
        }
    }
}

// ---------------- Correction: seg1 tokens += D_m * (pq . S_init) ----------------
__global__ __launch_bounds__(512, 4) void corr_kernel(
    const _Float16* __restrict__ qh, const float* __restrict__ gse_buf,
    const float* __restrict__ S0, const float* __restrict__ sk0,
    const float* __restrict__ Sloc, const float* __restrict__ skloc,
    float* __restrict__ den_buf, _Float16* __restrict__ part)
{
    const int bid = blockIdx.x;          // 1024 blocks: (bh 32, eh 8, dh 2, h2 2)
    const int bh = (bid & 7) * 4 + (bid >> 8);
    const int inner = (bid >> 3) & 31;
    const int eh = inner & 7, dh = (inner >> 3) & 1, h2 = inner >> 4;
    const int tid = threadIdx.x, lane = tid & 63, w = tid >> 6;
    const int nlane = lane & 15, quad = lane >> 4;

    __shared__ __align__(16) _Float16 sT[32 * STR_];
    __shared__ __align__(16) _Float16 qsh[64 * 64];
    __shared__ __align__(16) _Float16 sk_s[EPAD_];
    __shared__ int blk_s[NBLK_];

    for (int t = tid; t < NBLK_; t += 512) {
        int g = eh * NBLK_ + t;
        int i = 0;
        while (g >= 8 - (i >> 3)) { g -= 8 - (i >> 3); ++i; }
        int jb = (i >> 3) + g;
        blk_s[t] = i | (jb << 8);
    }
    __syncthreads();

    // decay products: dec0 = prod gse[0..31]; Dst = prod gse[32 .. 32+h2*16-1]
    float dec0 = 1.f, D = 1.f;
    for (int j = 0; j < SEGCH_; ++j) dec0 *= gse_buf[bh * NCH_ + j];
    for (int j = 0; j < h2 * 16; ++j) D *= gse_buf[bh * NCH_ + SEGCH_ + j];

    // ---- S_init = dec0 * S0hat + Sloc, f16 swizzled into sT
    const float* SL = Sloc + (size_t)(((bh << 3) + eh) * 2 + dh) * 9216;
    for (int p = tid; p < 32 * EPAD_; p += 512) {
        int dl = p / EPAD_;
        int e = p - dl * EPAD_;
        int bv = blk_s[e >> 3];
        int i = bv & 255, j8 = (bv >> 8) * 8 + (e & 7);
        float sv = 0.f;
        if (j8 >= i) {
            int er = (i * (129 - i)) / 2 + (j8 - i);
            float coef = (j8 == i) ? 1.f : 1.41421356237f;
            sv = dec0 * coef * S0[((size_t)bh * E_ + er) * 64 + dh * 32 + dl] + SL[e * 32 + dl];
        }
        int col8 = e >> 3, gsw = (dl >> 2) & 3;
        int pc = ((col8 & ~3) | ((col8 & 3) ^ gsw)) * 8 + (e & 7);
        sT[dl * STR_ + pc] = (_Float16)sv;
    }
    for (int e = tid; e < EPAD_; e += 512) {
        int bv = blk_s[e >> 3];
        int i = bv & 255, j8 = (bv >> 8) * 8 + (e & 7);
        float sv = 0.f;
        if (j8 >= i) {
            int er = (i * (129 - i)) / 2 + (j8 - i);
            float coef = (j8 == i) ? 1.f : 1.41421356237f;
            sv = dec0 * coef * sk0[(size_t)bh * E_ + er] + skloc[(size_t)((bh << 3) + eh) * EPAD_ + e];
        }
        sk_s[e] = (_Float16)sv;
    }

    const int mt = w & 3, nt0 = w >> 2;
    const int c_row = mt * 16 + nlane;
    const bool den_w = (w < 4) && (dh == 0);

    int qiu_off[NKS_], qrow_off[NKS_];
    #pragma unroll
    for (int ks = 0; ks < NKS_; ++ks) {
        int bv = blk_s[ks * 4 + quad];
        int ib = bv & 255, jb = bv >> 8;
        qiu_off[ks]  = (c_row * 64 + (((ib >> 3) ^ (c_row & 7)) << 3) + (ib & 7)) * 2;
        qrow_off[ks] = (c_row * 64 + ((jb ^ (c_row & 7)) << 3)) * 2;
    }
    const int b0_off = ((nt0 * 16 + nlane) * STR_ + ((quad ^ ((nlane >> 2) & 3)) << 3)) * 2;

    _Float16* ppart = part + (size_t)eh * OUTN_ + (((size_t)bh * T_) << 6) + dh * 32 + nt0 * 16 + nlane;

    const int gn_base = SEGCH_ + h2 * 16;
    for (int m = 0; m < 16; ++m) {
        const int gn = gn_base + m;
        __syncthreads();   // prev chunk's qsh reads done
        gload16(qh + ((size_t)(bh * NCH_) + gn) * 4096 + tid * 8, &qsh[tid * 8]);
        __syncthreads();   // qsh staged

        floatx4 acc0 = {0.f, 0.f, 0.f, 0.f};
        floatx4 acc1 = {0.f, 0.f, 0.f, 0.f};
        #pragma unroll
        for (int ks = 0; ks < NKS_; ++ks) {
            ushort qiu = *(const ushort*)((const char*)qsh + qiu_off[ks]);
            unsigned qi2 = ((unsigned)qiu << 16) | qiu;
            U8 qv; qv.u[0] = qi2; qv.u[1] = qi2; qv.u[2] = qi2; qv.u[3] = qi2;
            half8v qrow = *(const half8v*)((const char*)qsh + qrow_off[ks]);
            half8v afr = qv.h * qrow;
            half8v b0 = *(const half8v*)((const char*)sT + b0_off + ks * 64);
            acc0 = __builtin_amdgcn_mfma_f32_16x16x32_f16(afr, b0, acc0, 0, 0, 0);
            if (den_w) {
                half8v b1 = (half8v){0, 0, 0, 0, 0, 0, 0, 0};
                if (nlane == 0) b1 = *(const half8v*)&sk_s[ks * 32 + quad * 8];
                acc1 = __builtin_amdgcn_mfma_f32_16x16x32_f16(afr, b1, acc1, 0, 0, 0);
            }
        }
        _Float16* pp = ppart + ((size_t)(gn * CHUNK_ + mt * 16 + quad * 4) << 6);
        #pragma unroll
        for (int r = 0; r < 4; ++r) {
            size_t ix = (size_t)r << 6;
            pp[ix] = (_Float16)((float)pp[ix] + D * acc0[r]);
        }
        if (den_w && nlane == 0) {
            #pragma unroll
            for (int r = 0; r < 4; ++r)
                atomicAdd(&den_buf[(size_t)bh * T_ + gn * CHUNK_ + mt * 16 + quad * 4 + r], D * acc1[r]);
        }
        D *= gse_buf[bh * NCH_ + gn];
    }
}

// ---------------- Kernel A+C: intra-chunk attention (fp32) + merge ----------------
__global__ __launch_bounds__(256) void intra_merge_kernel(
    const float* __restrict__ q, const float* __restrict__ k, const float* __restrict__ v,
    const float* __restrict__ gate, const float* __restrict__ den_buf,
    const _Float16* __restrict__ part, float* __restrict__ out)
{
    const int bid = blockIdx.x;
    const int n = bid & 63, h = (bid >> 6) & 15, b = bid >> 10;
    const int tid = threadIdx.x;
    const int lane = tid & 63, w = tid >> 6;
    const int t0 = n * CHUNK_;
    const int bh = b * H_ + h;

    __shared__ float qs2[64 * 68];
    __shared__ float ks2[64 * 68];
    __shared__ float ss[64 * 68];
    __shared__ float cgs[64];
    __shared__ float dens[64];

    if (w == 0) {
        float g = gate[((size_t)(b * T_ + t0) + lane) * H_ + h];
        cgs[lane] = wave_iscan(g, lane);
    }
    for (int idx = tid; idx < 1024; idx += 256) {
        int c = idx >> 4, d4 = (idx & 15) << 2;
        size_t gi = ((size_t)(b * T_ + t0 + c) * H_ + h) * 64 + d4;
        *(float4*)&qs2[c * 68 + d4] = *(const float4*)&q[gi];
        *(float4*)&ks2[c * 68 + d4] = *(const float4*)&k[gi];
    }
    __syncthreads();

    const int tc = tid & 15, tm = tid >> 4;
    float acc[4][4] = {};
    for (int d4 = 0; d4 < 64; d4 += 4) {
        float4 qa[4], kb[4];
        #pragma unroll
        for (int i = 0; i < 4; ++i) qa[i] = *(const float4*)&qs2[(tc * 4 + i) * 68 + d4];
        #pragma unroll
        for (int j = 0; j < 4; ++j) kb[j] = *(const float4*)&ks2[(tm * 4 + j) * 68 + d4];
        #pragma unroll
        for (int i = 0; i < 4; ++i)
            #pragma unroll
            for (int j = 0; j < 4; ++j)
                acc[i][j] += qa[i].x * kb[j].x + qa[i].y * kb[j].y
                           + qa[i].z * kb[j].z + qa[i].w * kb[j].w;
    }
    #pragma unroll
    for (int i = 0; i < 4; ++i) {
        int c = tc * 4 + i;
        #pragma unroll
        for (int j = 0; j < 4; ++j) {
            int m = tm * 4 + j;
            float sv = 0.f;
            if (m <= c) {
                float qk = acc[i][j];
                sv = qk * qk * 0.015625f * __expf(cgs[c] - cgs[m]);
            }
            ss[c * 68 + m] = sv;
        }
    }
    __syncthreads();
    if (tid < 64) {
        float dsum = 0.f;
        #pragma unroll 8
        for (int m = 0; m < 64; ++m) dsum += ss[tid * 68 + m];
        dens[tid] = dsum;
    }
    for (int idx = tid; idx < 1024; idx += 256) {
        int c = idx >> 4, d4 = (idx & 15) << 2;
        size_t gi = ((size_t)(b * T_ + t0 + c) * H_ + h) * 64 + d4;
        *(float4*)&qs2[c * 68 + d4] = *(const float4*)&v[gi];
    }
    __syncthreads();

    float nacc[4][4] = {};
    for (int m = 0; m < 64; ++m) {
        float4 vb = *(const float4*)&qs2[m * 68 + tm * 4];
        float sa[4];
        #pragma unroll
        for (int i = 0; i < 4; ++i) sa[i] = ss[(tc * 4 + i) * 68 + m];
        #pragma unroll
        for (int i = 0; i < 4; ++i) {
            nacc[i][0] += sa[i] * vb.x;
            nacc[i][1] += sa[i] * vb.y;
            nacc[i][2] += sa[i] * vb.z;
            nacc[i][3] += sa[i] * vb.w;
        }
    }
    #pragma unroll
    for (int i = 0; i < 4; ++i)
        #pragma unroll
        for (int j = 0; j < 4; ++j)
            ks2[(tc * 4 + i) * 68 + tm * 4 + j] = nacc[i][j];
    __syncthreads();

    for (int idx = tid; idx < 4096; idx += 256) {
        int c = idx >> 6, d = idx & 63;
        float sum = ks2[c * 68 + d];
        size_t pb = (((size_t)bh * T_ + t0 + c) << 6) + d;
        #pragma unroll
        for (int ehh = 0; ehh < EH_; ++ehh)
            sum += (float)part[(size_t)ehh * OUTN_ + pb];
        float den = dens[c] + den_buf[(size_t)bh * T_ + t0 + c];
        out[((size_t)(b * T_ + t0 + c) * H_ + h) * 64 + d] = sum / fmaxf(den, 1.0f);
    }
}

extern "C" void kernel_launch(void* const* d_in, const int* in_sizes, int n_in,
                              void* d_out, int out_size, void* d_ws, size_t ws_size,
                              hipStream_t stream)
{
    (void)in_sizes; (void)n_in; (void)out_size; (void)ws_size;
    const float* q   = (const float*)d_in[0];
    const float* k   = (const float*)d_in[1];
    const float* v   = (const float*)d_in[2];
    const float* g   = (const float*)d_in[3];
    const float* S0  = (const float*)d_in[4];
    const float* sk0 = (const float*)d_in[5];
    float* out = (float*)d_out;

    // ws: den f32 | part f16 [EH][BHT D] | qh/khT/vhT f16 | gse f32 | Sloc f32 | skloc f32
    char* wp = (char*)d_ws;
    float*    den_buf = (float*)wp;                 wp += (size_t)B_ * H_ * T_ * sizeof(float);
    _Float16* part    = (_Float16*)wp;              wp += (size_t)EH_ * OUTN_ * sizeof(_Float16);
    _Float16* qh      = (_Float16*)wp;              wp += (size_t)B_ * H_ * T_ * D_ * sizeof(_Float16);
    _Float16* khT     = (_Float16*)wp;              wp += (size_t)B_ * H_ * T_ * D_ * sizeof(_Float16);
    _Float16* vhT     = (_Float16*)wp;              wp += (size_t)B_ * H_ * T_ * D_ * sizeof(_Float16);
    float*    gse_buf = (float*)wp;                 wp += (size_t)B_ * H_ * NCH_ * sizeof(float);
    float*    Sloc    = (float*)wp;                 wp += (size_t)B_ * H_ * EH_ * 2 * 9216 * sizeof(float);
    float*    skloc   = (float*)wp;

    hipMemsetAsync(den_buf, 0, (size_t)B_ * H_ * T_ * sizeof(float), stream);
    prep_kernel<<<dim3(2048), dim3(256), 0, stream>>>(q, k, v, g, qh, khT, vhT, gse_buf);
    scan_kernel<<<dim3(1024), dim3(512), 0, stream>>>(qh, khT, vhT, gse_buf, S0, sk0,
                                                      den_buf, part, Sloc, skloc);
    corr_kernel<<<dim3(1024), dim3(512), 0, stream>>>(qh, gse_buf, S0, sk0, Sloc, skloc,
                                                      den_buf, part);
    intra_merge_kernel<<<dim3(2048), dim3(256), 0, stream>>>(q, k, v, g, den_buf, part, out);
}

// Round 5
// 533.078 us; speedup vs baseline: 1.3130x; 1.3130x over previous
//
#include <hip/hip_runtime.h>

// Power retention (deg-2), B=2 T=4096 H=16 D=64, CHUNK=64, E=2080.
// Round 8: scan reverted to the PROVEN round-4 structure (370us, passed).
// Wave-specialized pipeline (R6/R7) abandoned: R7 failed correctness with a
// defect not localizable from source. New this round: MFMA merge kernel.
//  - prep additionally writes kh (row-major k~, qh-style swizzle).
//  - intra_merge now works entirely on hatted f16 operands:
//    s[c][m] = (q~.k~)^2 * e^{-gs} * causal-mask  (all gate math folded),
//    QK^T and PV via 16x16x32 f16 MFMAs with the scan's proven fragment
//    reads; den via shfl_xor row-reduce; tail (part-sum + divide) verbatim.

#define B_ 2
#define T_ 4096
#define H_ 16
#define D_ 64
#define CHUNK_ 64
#define NCH_ 64
#define E_ 2080
#define EH_ 8
#define NBLK_ 36         // (i, jb) 8-wide blocks per eh-slice (288/8, exact)
#define EPAD_ 288        // NBLK_*8
#define NKS_ 9           // MM1 K-steps of 32
#define STR_ 296         // sT row stride (f16), 592B
#define OUTN_ 8388608    // B*T*H*D

typedef __attribute__((ext_vector_type(8))) _Float16 half8v;
typedef __attribute__((ext_vector_type(4))) float floatx4;

union U8 { half8v h; unsigned u[4]; ushort s[8]; };

static __device__ __forceinline__ float wave_iscan(float g, int lane) {
    #pragma unroll
    for (int off = 1; off < 64; off <<= 1) {
        float o = __shfl_up(g, off, 64);
        if (lane >= off) g += o;
    }
    return g;
}

typedef const __attribute__((address_space(1))) unsigned int* gas1_t;
typedef __attribute__((address_space(3))) unsigned int* las3_t;
static __device__ __forceinline__ void gload16(const void* g, void* l) {
    __builtin_amdgcn_global_load_lds((gas1_t)g, (las3_t)l, 16, 0, 0);
}

// ---------------- Prep: gates + scales + cvt + swizzled transpose ----------------
// qh : [bh][n][c][ ((d>>3) ^ (c&7))*8 + (d&7) ]            q~ = 0.125*exp(0.5*cg)*q
// kh : [bh][n][c][ ((d>>3) ^ (c&7))*8 + (d&7) ]            k~ = exp(0.5*(gs-cg))*k
// khT: [bh][n][d][ ((c>>3) ^ (d&7) ^ (d>>3))*8 + (c&7) ]
// vhT: [bh][n][d][ ((c>>3) ^ (dl&7) ^ (dl>>3))*8 + (c&7) ] dl = d&31 (dh halves)
__global__ __launch_bounds__(256) void prep_kernel(
    const float* __restrict__ q, const float* __restrict__ k, const float* __restrict__ v,
    const float* __restrict__ gate,
    _Float16* __restrict__ qh, _Float16* __restrict__ kh, _Float16* __restrict__ khT,
    _Float16* __restrict__ vhT, float* __restrict__ gse_buf)
{
    const int bid = blockIdx.x;          // bh*64 + n
    const int bh = bid >> 6, n = bid & 63;
    const int b = bh >> 4, h = bh & 15;
    const int t0 = n * CHUNK_;
    const int tid = threadIdx.x;

    __shared__ float cgs[64];
    __shared__ float tbuf[64 * 68];

    if (tid < 64) {
        float g = gate[((size_t)(b * T_ + t0) + tid) * H_ + h];
        cgs[tid] = wave_iscan(g, tid);
    }
    __syncthreads();
    const float gs = cgs[63];
    if (tid == 0) gse_buf[bid] = __expf(gs);

    const int c = tid >> 2, dq = (tid & 3) * 16;
    const size_t gbase = ((size_t)(b * T_ + t0 + c) * H_ + h) * 64 + dq;
    const size_t obase = (size_t)bid * 4096;

    // ---- q~ (no transpose, swizzled d-groups)
    {
        float qsc = 0.125f * __expf(0.5f * cgs[c]);
        #pragma unroll
        for (int g8 = 0; g8 < 2; ++g8) {
            float4 a0 = *(const float4*)(q + gbase + g8 * 8);
            float4 a1 = *(const float4*)(q + gbase + g8 * 8 + 4);
            half8v hv;
            hv[0] = (_Float16)(a0.x * qsc); hv[1] = (_Float16)(a0.y * qsc);
            hv[2] = (_Float16)(a0.z * qsc); hv[3] = (_Float16)(a0.w * qsc);
            hv[4] = (_Float16)(a1.x * qsc); hv[5] = (_Float16)(a1.y * qsc);
            hv[6] = (_Float16)(a1.z * qsc); hv[7] = (_Float16)(a1.w * qsc);
            int grp = (dq >> 3) + g8;
            *(half8v*)&qh[obase + (size_t)(c * 64) + ((grp ^ (c & 7)) << 3)] = hv;
        }
    }
    // ---- k~ -> kh (row-major, q-style swizzle) + LDS [c][d]
    {
        float ksc = __expf(0.5f * (gs - cgs[c]));
        float4 sa[4];
        #pragma unroll
        for (int i = 0; i < 4; ++i) {
            float4 a = *(const float4*)(k + gbase + i * 4);
            sa[i].x = a.x * ksc; sa[i].y = a.y * ksc;
            sa[i].z = a.z * ksc; sa[i].w = a.w * ksc;
            *(float4*)&tbuf[c * 68 + dq + i * 4] = sa[i];
        }
        #pragma unroll
        for (int g8 = 0; g8 < 2; ++g8) {
            half8v hv;
            hv[0] = (_Float16)sa[g8 * 2].x;     hv[1] = (_Float16)sa[g8 * 2].y;
            hv[2] = (_Float16)sa[g8 * 2].z;     hv[3] = (_Float16)sa[g8 * 2].w;
            hv[4] = (_Float16)sa[g8 * 2 + 1].x; hv[5] = (_Float16)sa[g8 * 2 + 1].y;
            hv[6] = (_Float16)sa[g8 * 2 + 1].z; hv[7] = (_Float16)sa[g8 * 2 + 1].w;
            int grp = (dq >> 3) + g8;
            *(half8v*)&kh[obase + (size_t)(c * 64) + ((grp ^ (c & 7)) << 3)] = hv;
        }
    }
    __syncthreads();
    {   // transposed, swizzled store of k~^T
        int d = tid & 63, f = (d & 7) ^ (d >> 3);
        #pragma unroll
        for (int gg = 0; gg < 2; ++gg) {
            int cg = (tid >> 6) * 2 + gg;
            half8v hv;
            #pragma unroll
            for (int j = 0; j < 8; ++j) hv[j] = (_Float16)tbuf[(cg * 8 + j) * 68 + d];
            *(half8v*)&khT[obase + (size_t)(d * 64) + ((cg ^ f) << 3)] = hv;
        }
    }
    __syncthreads();
    {   // v -> LDS (no scale)
        #pragma unroll
        for (int i = 0; i < 4; ++i)
            *(float4*)&tbuf[c * 68 + dq + i * 4] = *(const float4*)(v + gbase + i * 4);
    }
    __syncthreads();
    {   // transposed, swizzled store of v^T (f over dl = d&31)
        int d = tid & 63, dl = d & 31, f = (dl & 7) ^ (dl >> 3);
        #pragma unroll
        for (int gg = 0; gg < 2; ++gg) {
            int cg = (tid >> 6) * 2 + gg;
            half8v hv;
            #pragma unroll
            for (int j = 0; j < 8; ++j) hv[j] = (_Float16)tbuf[(cg * 8 + j) * 68 + d];
            *(half8v*)&vhT[obase + (size_t)(d * 64) + ((cg ^ f) << 3)] = hv;
        }
    }
}

// ---------------- Kernel B: sequential scan over chunks (f16 MFMA) ----------------
// PROVEN round-4 structure, verbatim.
__global__ __launch_bounds__(512, 4) void scan_kernel(
    const _Float16* __restrict__ qh, const _Float16* __restrict__ khT,
    const _Float16* __restrict__ vhT, const float* __restrict__ gse_buf,
    const float* __restrict__ S0, const float* __restrict__ sk0,
    float* __restrict__ den_buf, _Float16* __restrict__ part)
{
    const int bid = blockIdx.x;
    // XCD swizzle: all 16 blocks of one bh share bid%8 -> same XCD for q/k/v L2 reuse
    const int bh = (bid & 7) * 4 + (bid >> 7);
    const int inner = (bid >> 3) & 15;
    const int eh = inner & 7, dh = inner >> 3;
    const int tid = threadIdx.x, lane = tid & 63, w = tid >> 6;   // w 0..7
    const int nlane = lane & 15, quad = lane >> 4;

    __shared__ __align__(16) _Float16 sT[32 * STR_];     // S^T[d_local][e], 2-bit XOR swz
    __shared__ __align__(16) _Float16 kTs[64 * 64];      // k~^T (linear, global-preswizzled)
    __shared__ __align__(16) _Float16 qsh[64 * 64];      // q~   (linear, global-preswizzled)
    __shared__ __align__(16) _Float16 vTs[32 * 64];      // v^T half (linear, preswizzled)
    __shared__ __align__(16) _Float16 sk_s[EPAD_];
    __shared__ int blk_s[NBLK_];                         // i | (jb<<8)

    // ---- build (i, jb) block table for this slice
    for (int t = tid; t < NBLK_; t += 512) {
        int g = eh * NBLK_ + t;
        int i = 0;
        while (g >= 8 - (i >> 3)) { g -= 8 - (i >> 3); ++i; }
        int jb = (i >> 3) + g;
        blk_s[t] = i | (jb << 8);
    }
    __syncthreads();

    const _Float16* qsrc = qh + (size_t)(bh * NCH_) * 4096;
    const _Float16* ksrc = khT + (size_t)(bh * NCH_) * 4096;
    const _Float16* vsrc = vhT + (size_t)(bh * NCH_) * 4096 + dh * 2048;

    // issue q~(0) staging now; drains at the pre-loop barrier
    gload16(qsrc + tid * 8, &qsh[tid * 8]);

    // ---- sk init (sqrt2 fold; invalid slots stay 0 forever -> no m8 mask needed)
    for (int e = tid; e < EPAD_; e += 512) {
        int bv = blk_s[e >> 3];
        int i = bv & 255, j8 = (bv >> 8) * 8 + (e & 7);
        float sv = 0.f;
        if (j8 >= i) {
            int er = (i * (129 - i)) / 2 + (j8 - i);
            float coef = (j8 == i) ? 1.f : 1.41421356237f;
            sv = sk0[(size_t)bh * E_ + er] * coef;
        }
        sk_s[e] = (_Float16)sv;
    }
    // ---- sT init (f16 copy of S-hat = coef * S0), 2-bit XOR swizzled columns
    for (int p = tid; p < 32 * EPAD_; p += 512) {
        int dl = p / EPAD_;
        int e = p - dl * EPAD_;
        int bv = blk_s[e >> 3];
        int i = bv & 255, j8 = (bv >> 8) * 8 + (e & 7);
        float sv = 0.f;
        if (j8 >= i) {
            int er = (i * (129 - i)) / 2 + (j8 - i);
            float coef = (j8 == i) ? 1.f : 1.41421356237f;
            sv = S0[((size_t)bh * E_ + er) * 64 + dh * 32 + dl] * coef;
        }
        int col8 = e >> 3, gsw = (dl >> 2) & 3;
        int pc = ((col8 & ~3) | ((col8 & 3) ^ gsw)) * 8 + (e & 7);
        sT[dl * STR_ + pc] = (_Float16)sv;
    }

    // ---- wave roles
    const int mt = w & 3, nt0 = w >> 2;
    const int c_row = mt * 16 + nlane;
    const bool den_w = (w < 4) && (dh == 0);
    const int NTS = (w < 2) ? 3 : 2;          // waves 0,1 own a 3rd tile (16,17)

    // ---- resident S fragments: wave owns tiles {w, w+8, (w+16 if w<2)} x mtv{0,1}(+sk)
    floatx4 res[3][2];
    floatx4 resk[3];
    #pragma unroll
    for (int ts = 0; ts < 3; ++ts) {
        res[ts][0] = (floatx4){0.f, 0.f, 0.f, 0.f};
        res[ts][1] = (floatx4){0.f, 0.f, 0.f, 0.f};
        resk[ts]   = (floatx4){0.f, 0.f, 0.f, 0.f};
        if (ts >= NTS) continue;
        int tile = w + 8 * ts;
        int e = tile * 16 + nlane;
        int bv = blk_s[e >> 3];
        int i = bv & 255, j8 = (bv >> 8) * 8 + (e & 7);
        if (j8 >= i) {
            int er = (i * (129 - i)) / 2 + (j8 - i);
            float coef = (j8 == i) ? 1.f : 1.41421356237f;
            #pragma unroll
            for (int m = 0; m < 2; ++m) {
                floatx4 t4 = *(const floatx4*)&S0[((size_t)bh * E_ + er) * 64 + dh * 32 + m * 16 + quad * 4];
                #pragma unroll
                for (int r = 0; r < 4; ++r) res[ts][m][r] = t4[r] * coef;
            }
            if (dh == 0 && quad == 0) resk[ts][0] = sk0[(size_t)bh * E_ + er] * coef;
        }
    }

    // ---- chunk-invariant MM1 addresses (byte offsets)
    int qiu_off[NKS_], qrow_off[NKS_];
    #pragma unroll
    for (int ks = 0; ks < NKS_; ++ks) {
        int bv = blk_s[ks * 4 + quad];
        int ib = bv & 255, jb = bv >> 8;
        qiu_off[ks]  = (c_row * 64 + (((ib >> 3) ^ (c_row & 7)) << 3) + (ib & 7)) * 2;
        qrow_off[ks] = (c_row * 64 + ((jb ^ (c_row & 7)) << 3)) * 2;
    }
    const int b0_off = ((nt0 * 16 + nlane) * STR_ + ((quad ^ ((nlane >> 2) & 3)) << 3)) * 2;

    // ---- chunk-invariant MM2 addresses + m2 splats
    int pa_off[3], pb_off[3], stw_off[3], eidx[3];
    unsigned m2sp[3];
    #pragma unroll
    for (int ts = 0; ts < 3; ++ts) {
        pa_off[ts] = pb_off[ts] = stw_off[ts] = eidx[ts] = 0; m2sp[ts] = 0;
        if (ts >= NTS) continue;
        int tile = w + 8 * ts, e = tile * 16 + nlane;
        int bv = blk_s[e >> 3];
        int ib = bv & 255, j8 = (bv >> 8) * 8 + (e & 7);
        int fib = (ib & 7) ^ (ib >> 3), fj8 = (j8 & 7) ^ (j8 >> 3);
        pa_off[ts] = (ib * 64 + ((quad ^ fib) << 3)) * 2;
        pb_off[ts] = (j8 * 64 + ((quad ^ fj8) << 3)) * 2;
        int col8 = e >> 3;
        int pc = ((col8 & ~3) | ((col8 & 3) ^ quad)) * 8 + (e & 7);
        stw_off[ts] = (quad * 4 * STR_ + pc) * 2;
        eidx[ts] = e;
        unsigned hv = (j8 < ib) ? 0u : ((j8 == ib) ? 0x3C00u : 0x4000u);  // {0,1,2} coef^2
        m2sp[ts] = (hv << 16) | hv;
    }
    int af_off[2];
    #pragma unroll
    for (int m = 0; m < 2; ++m) {
        int row = m * 16 + nlane;
        int fr = (row & 7) ^ (row >> 3);
        af_off[m] = (row * 64 + ((quad ^ fr) << 3)) * 2;
    }
    half8v af_sk = (half8v){0, 0, 0, 0, 0, 0, 0, 0};
    if (nlane == 0) af_sk = (half8v){1, 1, 1, 1, 1, 1, 1, 1};

    _Float16* ppart = part + (size_t)eh * OUTN_ + (((size_t)bh * T_) << 6) + dh * 32 + nt0 * 16 + nlane;

    __syncthreads();   // B0: init + blk reads done; q~(0) drained

    for (int n = 0; n < NCH_; ++n) {
        // issue k~/v staging for THIS chunk; drains at B2 (hidden under MM1)
        gload16(ksrc + (size_t)n * 4096 + tid * 8, &kTs[tid * 8]);
        if (tid < 256) gload16(vsrc + (size_t)n * 4096 + tid * 8, &vTs[tid * 8]);
        const float gsev = gse_buf[bh * NCH_ + n];

        // ======== MM1: num[c][d] = pq . S-hat ; den rides as MFMA with sk column
        {
            floatx4 acc0 = {0.f, 0.f, 0.f, 0.f};
            floatx4 acc1 = {0.f, 0.f, 0.f, 0.f};
            #pragma unroll
            for (int ks = 0; ks < NKS_; ++ks) {
                ushort qiu = *(const ushort*)((const char*)qsh + qiu_off[ks]);
                unsigned qi2 = ((unsigned)qiu << 16) | qiu;
                U8 qv; qv.u[0] = qi2; qv.u[1] = qi2; qv.u[2] = qi2; qv.u[3] = qi2;
                half8v qrow = *(const half8v*)((const char*)qsh + qrow_off[ks]);
                half8v afr = qv.h * qrow;            // no m8: invalid sT cols are 0
                half8v b0 = *(const half8v*)((const char*)sT + b0_off + ks * 64);
                acc0 = __builtin_amdgcn_mfma_f32_16x16x32_f16(afr, b0, acc0, 0, 0, 0);
                if (den_w) {
                    half8v b1 = (half8v){0, 0, 0, 0, 0, 0, 0, 0};
                    if (nlane == 0) b1 = *(const half8v*)&sk_s[ks * 32 + quad * 8];
                    acc1 = __builtin_amdgcn_mfma_f32_16x16x32_f16(afr, b1, acc1, 0, 0, 0);
                }
            }
            _Float16* pp = ppart + ((size_t)(n * CHUNK_ + mt * 16 + quad * 4) << 6);
            #pragma unroll
            for (int r = 0; r < 4; ++r) pp[(size_t)r << 6] = (_Float16)acc0[r];
            if (den_w && nlane == 0) {
                #pragma unroll
                for (int r = 0; r < 4; ++r)
                    atomicAdd(&den_buf[(size_t)bh * T_ + n * CHUNK_ + mt * 16 + quad * 4 + r], acc1[r]);
            }
        }
        __syncthreads();   // B2: MM1 LDS reads done; k~/v staged

        // issue q~(n+1); drains at B1 (hidden under MM2)
        if (n + 1 < NCH_) gload16(qsrc + (size_t)(n + 1) * 4096 + tid * 8, &qsh[tid * 8]);

        // ======== MM2: S-hat = gse*S-hat + v^T . pk ; sk rides as ones-row unit
        #pragma unroll
        for (int ts = 0; ts < 3; ++ts) {
            if (ts >= NTS) continue;
            #pragma unroll
            for (int m = 0; m < 2; ++m)
                #pragma unroll
                for (int r = 0; r < 4; ++r) res[ts][m][r] *= gsev;
            if (dh == 0) resk[ts][0] *= gsev;
        }
        #pragma unroll
        for (int k2 = 0; k2 < 2; ++k2) {
            const int xo = k2 * 64;    // group bit2 flip == byte bit6 flip
            half8v af0 = *(const half8v*)((const char*)vTs + (af_off[0] ^ xo));
            half8v af1 = *(const half8v*)((const char*)vTs + (af_off[1] ^ xo));
            #pragma unroll
            for (int ts = 0; ts < 3; ++ts) {
                if (ts >= NTS) continue;
                half8v pa = *(const half8v*)((const char*)kTs + (pa_off[ts] ^ xo));
                half8v pb = *(const half8v*)((const char*)kTs + (pb_off[ts] ^ xo));
                U8 mv; mv.u[0] = m2sp[ts]; mv.u[1] = m2sp[ts]; mv.u[2] = m2sp[ts]; mv.u[3] = m2sp[ts];
                half8v bfr = pa * pb * mv.h;
                res[ts][0] = __builtin_amdgcn_mfma_f32_16x16x32_f16(af0, bfr, res[ts][0], 0, 0, 0);
                res[ts][1] = __builtin_amdgcn_mfma_f32_16x16x32_f16(af1, bfr, res[ts][1], 0, 0, 0);
                if (dh == 0)
                    resk[ts] = __builtin_amdgcn_mfma_f32_16x16x32_f16(af_sk, bfr, resk[ts], 0, 0, 0);
            }
        }
        // write back sT (swizzled, 2-way max) and sk
        #pragma unroll
        for (int ts = 0; ts < 3; ++ts) {
            if (ts >= NTS) continue;
            #pragma unroll
            for (int m = 0; m < 2; ++m)
                #pragma unroll
                for (int r = 0; r < 4; ++r)
                    *(_Float16*)((char*)sT + stw_off[ts] + (m * 16 * STR_ + r * STR_) * 2) =
                        (_Float16)res[ts][m][r];
            if (dh == 0 && quad == 0) sk_s[eidx[ts]] = (_Float16)resk[ts][0];
        }
        __syncthreads();   // B1: sT/sk visible; q~(n+1) drained
    }
}

// ---------------- Kernel A+C: intra-chunk attention (f16 MFMA) + merge ----------------
__global__ __launch_bounds__(256) void intra_merge_kernel(
    const _Float16* __restrict__ qh, const _Float16* __restrict__ kh,
    const _Float16* __restrict__ vhT, const float* __restrict__ gse_buf,
    const float* __restrict__ den_buf, const _Float16* __restrict__ part,
    float* __restrict__ out)
{
    const int bid = blockIdx.x;
    const int n = bid & 63, h = (bid >> 6) & 15, b = bid >> 10;
    const int tid = threadIdx.x;
    const int lane = tid & 63, w = tid >> 6;     // 4 waves
    const int nlane = lane & 15, quad = lane >> 4;
    const int t0 = n * CHUNK_;
    const int bh = b * H_ + h;

    __shared__ __align__(16) _Float16 qs[4096];   // q~ [c][d-swz]
    __shared__ __align__(16) _Float16 ksm[4096];  // k~ [m][d-swz]
    __shared__ __align__(16) _Float16 vs[4096];   // v^T [d][c-swz]
    __shared__ __align__(16) _Float16 ss[4096];   // s  [c][m-swz] f16
    __shared__ float nbuf[64 * 68];
    __shared__ float dens[64];

    const size_t obase = (size_t)(bh * NCH_ + n) * 4096;
    gload16(qh + obase + tid * 8, &qs[tid * 8]);
    gload16(qh + obase + 2048 + tid * 8, &qs[2048 + tid * 8]);
    gload16(kh + obase + tid * 8, &ksm[tid * 8]);
    gload16(kh + obase + 2048 + tid * 8, &ksm[2048 + tid * 8]);
    gload16(vhT + obase + tid * 8, &vs[tid * 8]);
    gload16(vhT + obase + 2048 + tid * 8, &vs[2048 + tid * 8]);
    const float gsei = 1.0f / gse_buf[bh * NCH_ + n];
    __syncthreads();

    const int ct = w;
    const int crow = ct * 16 + nlane;
    const int cswz = crow & 7;

    // ======== QK^T: qk~[c][m] = sum_d q~[c][d] k~[m][d]  (16x16x32, K=d)
    floatx4 qk[4];
    #pragma unroll
    for (int mt = 0; mt < 4; ++mt) qk[mt] = (floatx4){0.f, 0.f, 0.f, 0.f};
    #pragma unroll
    for (int ks_ = 0; ks_ < 2; ++ks_) {
        int g = ks_ * 4 + quad;
        half8v a = *(const half8v*)&qs[crow * 64 + ((g ^ cswz) << 3)];
        #pragma unroll
        for (int mt = 0; mt < 4; ++mt) {
            int mrow = mt * 16 + nlane;
            half8v bf = *(const half8v*)&ksm[mrow * 64 + ((g ^ (mrow & 7)) << 3)];
            qk[mt] = __builtin_amdgcn_mfma_f32_16x16x32_f16(a, bf, qk[mt], 0, 0, 0);
        }
    }

    // ======== scores: s = qk~^2 * e^{-gs} * [m<=c]; den row-sum in-register
    float dsum[4] = {0.f, 0.f, 0.f, 0.f};
    #pragma unroll
    for (int mt = 0; mt < 4; ++mt) {
        int m = mt * 16 + nlane;
        #pragma unroll
        for (int r = 0; r < 4; ++r) {
            int c = ct * 16 + quad * 4 + r;
            float sv = qk[mt][r];
            sv = sv * sv * gsei;
            sv = (m <= c) ? sv : 0.f;
            dsum[r] += sv;
            ss[c * 64 + (((m >> 3) ^ (c & 7)) << 3) + (m & 7)] = (_Float16)sv;
        }
    }
    #pragma unroll
    for (int off = 1; off < 16; off <<= 1)
        #pragma unroll
        for (int r = 0; r < 4; ++r) dsum[r] += __shfl_xor(dsum[r], off, 64);
    if (nlane == 0) {
        #pragma unroll
        for (int r = 0; r < 4; ++r) dens[ct * 16 + quad * 4 + r] = dsum[r];
    }
    __syncthreads();   // ss + dens visible (defensive; ss deps are intra-wave)

    // ======== PV: num[c][d] = sum_m s[c][m] v[m][d]  (16x16x32, K=m)
    floatx4 num[4];
    #pragma unroll
    for (int dt = 0; dt < 4; ++dt) num[dt] = (floatx4){0.f, 0.f, 0.f, 0.f};
    #pragma unroll
    for (int ks_ = 0; ks_ < 2; ++ks_) {
        int g = ks_ * 4 + quad;
        half8v a = *(const half8v*)&ss[crow * 64 + ((g ^ cswz) << 3)];
        #pragma unroll
        for (int dt = 0; dt < 4; ++dt) {
            int d = dt * 16 + nlane, dl = d & 31;
            int f = (dl & 7) ^ (dl >> 3);
            half8v bf = *(const half8v*)&vs[d * 64 + ((g ^ f) << 3)];
            num[dt] = __builtin_amdgcn_mfma_f32_16x16x32_f16(a, bf, num[dt], 0, 0, 0);
        }
    }
    #pragma unroll
    for (int dt = 0; dt < 4; ++dt)
        #pragma unroll
        for (int r = 0; r < 4; ++r)
            nbuf[(ct * 16 + quad * 4 + r) * 68 + dt * 16 + nlane] = num[dt][r];
    __syncthreads();

    // ======== tail: add inter parts, divide, store (verbatim from round 4)
    for (int idx = tid; idx < 4096; idx += 256) {
        int c = idx >> 6, d = idx & 63;
        float sum = nbuf[c * 68 + d];
        size_t pb = (((size_t)bh * T_ + t0 + c) << 6) + d;
        #pragma unroll
        for (int ehh = 0; ehh < EH_; ++ehh)
            sum += (float)part[(size_t)ehh * OUTN_ + pb];
        float den = dens[c] + den_buf[(size_t)bh * T_ + t0 + c];
        out[((size_t)(b * T_ + t0 + c) * H_ + h) * 64 + d] = sum / fmaxf(den, 1.0f);
    }
}

extern "C" void kernel_launch(void* const* d_in, const int* in_sizes, int n_in,
                              void* d_out, int out_size, void* d_ws, size_t ws_size,
                              hipStream_t stream)
{
    (void)in_sizes; (void)n_in; (void)out_size; (void)ws_size;
    const float* q   = (const float*)d_in[0];
    const float* k   = (const float*)d_in[1];
    const float* v   = (const float*)d_in[2];
    const float* g   = (const float*)d_in[3];
    const float* S0  = (const float*)d_in[4];
    const float* sk0 = (const float*)d_in[5];
    float* out = (float*)d_out;

    // ws: den f32 | part f16 [EH][BHT D] | qh/khT/vhT/kh f16 (16.78MB each) | gse f32
    char* wp = (char*)d_ws;
    float*    den_buf = (float*)wp;                 wp += (size_t)B_ * H_ * T_ * sizeof(float);
    _Float16* part    = (_Float16*)wp;              wp += (size_t)EH_ * OUTN_ * sizeof(_Float16);
    _Float16* qh      = (_Float16*)wp;              wp += (size_t)B_ * H_ * T_ * D_ * sizeof(_Float16);
    _Float16* khT     = (_Float16*)wp;              wp += (size_t)B_ * H_ * T_ * D_ * sizeof(_Float16);
    _Float16* vhT     = (_Float16*)wp;              wp += (size_t)B_ * H_ * T_ * D_ * sizeof(_Float16);
    _Float16* kh      = (_Float16*)wp;              wp += (size_t)B_ * H_ * T_ * D_ * sizeof(_Float16);
    float*    gse_buf = (float*)wp;

    hipMemsetAsync(den_buf, 0, (size_t)B_ * H_ * T_ * sizeof(float), stream);
    prep_kernel<<<dim3(2048), dim3(256), 0, stream>>>(q, k, v, g, qh, kh, khT, vhT, gse_buf);
    scan_kernel<<<dim3(512), dim3(512), 0, stream>>>(qh, khT, vhT, gse_buf, S0, sk0, den_buf, part);
    intra_merge_kernel<<<dim3(2048), dim3(256), 0, stream>>>(qh, kh, vhT, gse_buf, den_buf, part, out);
}